// Round 12
// baseline (832.306 us; speedup 1.0000x reference)
//
#include <hip/hip_runtime.h>
#include <hip/hip_bf16.h>
#include <math.h>

#define KK    32
#define NG    1344        // grid points per table (21 * 64)
#define NCH   (NG / 64)   // 21 chunks of 64 grid points
#define XLO   (-6.5f)
#define GH    0.01f
#define INVH  100.0f
#define NBLK  2048        // exactly 8 blocks/CU * 256 CU -> all co-resident
#define NBUILD_BLK 336    // 1344 build waves / 4 waves per block

__device__ __forceinline__ float hw_exp2(float x) {
#if __has_builtin(__builtin_amdgcn_exp2f)
    return __builtin_amdgcn_exp2f(x);
#else
    float r;
    asm("v_exp_f32 %0, %1" : "=v"(r) : "v"(x));
    return r;
#endif
}

__device__ __forceinline__ float hw_log2(float x) {
#if __has_builtin(__builtin_amdgcn_logf)
    return __builtin_amdgcn_logf(x);
#else
    float r;
    asm("v_log_f32 %0, %1" : "=v"(r) : "v"(x));
    return r;
#endif
}

// Fused build+main. r11 showed exec ~3.5us but dur 16.4us: the budget gap is
// per-dispatch fixed cost (boundary drain + dispatch + wave ramp) x2 kernels.
// Fuse into one kernel; grid barrier is deadlock-free BY CONSTRUCTION:
// __launch_bounds__(256,8) caps VGPR at 64 -> 8 blocks/CU; LDS 16.5KB*8 =
// 132KB < 160KB -> all 2048 blocks co-resident. Cross-XCD visibility of the
// tables via __threadfence (agent-scope wb/inv) around the atomic barrier.
__global__ __launch_bounds__(256, 8) void tt_fused(
        const float2* __restrict__ X,
        const float* __restrict__ Wk0,
        const float* __restrict__ Wk1k0,
        const float* __restrict__ Wk2k1,
        const float* __restrict__ mu,
        const float* __restrict__ sigma,
        float* __restrict__ Gp,     // [NG][KK] float2 pairs (val[i], val[i+1])
        float* __restrict__ Hp,
        unsigned* __restrict__ ctr, // zeroed by memsetAsync each launch
        float* __restrict__ out,
        int ntot) {
    __shared__ float lmu[1024], lsig[1024], lw1[1024], lw2[1024], lw0[32];
    const int tid  = threadIdx.x;
    const int lane = tid & 63;

    // ================= BUILD PHASE (blocks 0..335, identical math to r11) ==
    if (blockIdx.x < NBUILD_BLK) {
#pragma unroll
        for (int r = 0; r < 4; ++r) {
            int o = r * 256 + tid;
            lmu[o]  = mu[o];
            lsig[o] = sigma[o];
            lw1[o]  = Wk1k0[o];
            lw2[o]  = Wk2k1[o];
        }
        if (tid < 32) lw0[tid] = Wk0[tid];
        __syncthreads();

        int wid = __builtin_amdgcn_readfirstlane((blockIdx.x * 256 + tid) >> 6);
        const int HALF = KK * NCH;                 // 672 waves per table
        const int table = wid >= HALF;             // scalar
        int rem   = table ? wid - HALF : wid;
        int k1    = rem / NCH;
        int chunk = rem - k1 * NCH;
        int i     = chunk * 64 + lane;             // per-lane grid index
        float x   = __builtin_fmaf((float)i, GH, XLO);

        const float LOG2E = 1.4426950408889634f;
        const float INV_SQRT_2PI = 0.3989422804014327f;

        float q[KK];
        float m = -3.0e38f;
#pragma unroll
        for (int k = 0; k < KK; ++k) {
            int idx = table ? (k1 * KK + k) : (k * KK + k1);   // wave-uniform
            float muv = lmu[idx];                              // ds broadcast
            float sv  = lsig[idx];
            float wv  = table ? (lw1[idx] * lw0[k]) : lw2[idx];
            float inv_s = 1.0f / sv;
            float z = (x - muv) * inv_s;
            float qq = __builtin_fmaf(-0.5f * LOG2E * z, z,
                                      hw_log2(wv * INV_SQRT_2PI * inv_s));
            q[k] = qq;
            m = fmaxf(m, qq);
        }
        float s = 0.0f;
#pragma unroll
        for (int k = 0; k < KK; ++k) s += hw_exp2(q[k] - m);
        float val = m + hw_log2(s);

        float* df = table ? Hp : Gp;               // pair array, float view
        df[(i * KK + k1) * 2] = val;               // pair[i].x = val[i]
        if (i > 0)
            df[((i - 1) * KK + k1) * 2 + 1] = val; // pair[i-1].y = val[i]
    }

    // ================= GRID BARRIER (device-scope, cross-XCD safe) =========
    __threadfence();            // release: drain stores, L2 writeback
    __syncthreads();
    if (tid == 0) {
        __hip_atomic_fetch_add(ctr, 1u, __ATOMIC_RELEASE,
                               __HIP_MEMORY_SCOPE_AGENT);
        while (__hip_atomic_load(ctr, __ATOMIC_ACQUIRE,
                                 __HIP_MEMORY_SCOPE_AGENT) < (unsigned)NBLK) {
            __builtin_amdgcn_s_sleep(2);
        }
    }
    __syncthreads();
    __threadfence();            // acquire: invalidate stale L2 table lines

    // ================= MAIN PHASE (identical math to r11) ==================
    const float4* G4 = (const float4*)Gp;
    const float4* H4 = (const float4*)Hp;
    const int kl8 = tid & 7;                   // which k1-quad this lane owns
    const int grp = (tid & 63) >> 3;           // sample slot within wave
    const int gw  = (blockIdx.x * 256 + tid) >> 6;
    const int stride = NBLK * 32;              // samples per grid pass
    const float LN2 = 0.6931471805599453f;

#pragma unroll 2
    for (int s = gw * 8 + grp; s < ntot; s += stride) {
        float2 x = X[s];                       // broadcast within 8-lane group

        float u1 = (x.y - XLO) * INVH;
        float u0 = (x.x - XLO) * INVH;
        int i1 = (int)u1; i1 = i1 < 0 ? 0 : (i1 > NG - 2 ? NG - 2 : i1);
        int i0 = (int)u0; i0 = i0 < 0 ? 0 : (i0 > NG - 2 ? NG - 2 : i0);
        float f1 = fminf(fmaxf(u1 - (float)i1, 0.0f), 1.0f);
        float f0 = fminf(fmaxf(u0 - (float)i0, 0.0f), 1.0f);

        int og = i1 * 16 + kl8 * 2;            // row = 32 float2 = 16 float4
        int oh = i0 * 16 + kl8 * 2;
        float4 ga = G4[og], gb = G4[og + 1];   // 4 k1's, both lerp endpoints
        float4 ha = H4[oh], hb = H4[oh + 1];

        float q0 = __builtin_fmaf(f1, ga.y - ga.x, ga.x)
                 + __builtin_fmaf(f0, ha.y - ha.x, ha.x);
        float q1 = __builtin_fmaf(f1, ga.w - ga.z, ga.z)
                 + __builtin_fmaf(f0, ha.w - ha.z, ha.z);
        float q2 = __builtin_fmaf(f1, gb.y - gb.x, gb.x)
                 + __builtin_fmaf(f0, hb.y - hb.x, hb.x);
        float q3 = __builtin_fmaf(f1, gb.w - gb.z, gb.z)
                 + __builtin_fmaf(f0, hb.w - hb.z, hb.z);
        float e = (hw_exp2(q0) + hw_exp2(q1)) + (hw_exp2(q2) + hw_exp2(q3));

        // sum over the 8-lane group (3 stages)
        e += __shfl_xor(e, 1, 8);
        e += __shfl_xor(e, 2, 8);
        e += __shfl_xor(e, 4, 8);

        if (kl8 == 0) out[s] = LN2 * hw_log2(e);
    }
}

extern "C" void kernel_launch(void* const* d_in, const int* in_sizes, int n_in,
                              void* d_out, int out_size, void* d_ws, size_t ws_size,
                              hipStream_t stream) {
    const float* X     = (const float*)d_in[0];
    const float* Wk0   = (const float*)d_in[1];
    const float* Wk1k0 = (const float*)d_in[2];
    const float* Wk2k1 = (const float*)d_in[3];
    const float* mu    = (const float*)d_in[4];
    const float* sigma = (const float*)d_in[5];
    float* out = (float*)d_out;

    // pair tables: NG*KK*8 B = 336 KB each; barrier counter after them
    const size_t TBL = (size_t)NG * KK * 8;
    float*    Gp  = (float*)d_ws;
    float*    Hp  = (float*)((char*)d_ws + TBL);
    unsigned* ctr = (unsigned*)((char*)d_ws + 2 * TBL);

    int ntot = in_sizes[0] / 2;  // N = 131072

    hipMemsetAsync(ctr, 0, sizeof(unsigned), stream);
    tt_fused<<<NBLK, 256, 0, stream>>>(
        (const float2*)X, Wk0, Wk1k0, Wk2k1, mu, sigma, Gp, Hp, ctr, out, ntot);
}

// Round 13
// 106.870 us; speedup vs baseline: 7.7880x; 7.7880x over previous
//
#include <hip/hip_runtime.h>
#include <hip/hip_bf16.h>
#include <math.h>

#define KK    32
#define NG    1344        // grid points per table (21 * 64)
#define NCH   (NG / 64)   // 21 chunks of 64 grid points
#define XLO   (-6.5f)
#define GH    0.01f
#define INVH  100.0f
#define NBLK  2048        // 8 blocks/CU * 256 CU -> all co-resident (r12: 98% occ)
#define NBUILD_BLK 336    // 1344 build waves / 4 waves per block

__device__ __forceinline__ float hw_exp2(float x) {
#if __has_builtin(__builtin_amdgcn_exp2f)
    return __builtin_amdgcn_exp2f(x);
#else
    float r;
    asm("v_exp_f32 %0, %1" : "=v"(r) : "v"(x));
    return r;
#endif
}

__device__ __forceinline__ float hw_log2(float x) {
#if __has_builtin(__builtin_amdgcn_logf)
    return __builtin_amdgcn_logf(x);
#else
    float r;
    asm("v_log_f32 %0, %1" : "=v"(r) : "v"(x));
    return r;
#endif
}

// Fused build+main (r12 structure; r12 proved correctness + co-residency but
// its barrier polled with AGENT-ACQUIRE loads -> a cache-maintenance op PER
// POLL ITERATION from 2048 blocks (832us, VALUBusy 0.5%, 18MB writeback).
// v2 sync: producer-consumer FLAG (only 336 build blocks arrive), RELAXED
// polls (no cache ops), exactly ONE release fence per build block and ONE
// acquire fence per block after the flag trips (tid0; block's 4 waves share
// the CU's L1, fence's L2-wb/inv is cache-wide per XCD).
__global__ __launch_bounds__(256, 8) void tt_fused(
        const float2* __restrict__ X,
        const float* __restrict__ Wk0,
        const float* __restrict__ Wk1k0,
        const float* __restrict__ Wk2k1,
        const float* __restrict__ mu,
        const float* __restrict__ sigma,
        float* __restrict__ Gp,     // [NG][KK] float2 pairs (val[i], val[i+1])
        float* __restrict__ Hp,
        unsigned* __restrict__ ctr, // zeroed by 4B memsetAsync each launch
        float* __restrict__ out,
        int ntot) {
    __shared__ float lmu[1024], lsig[1024], lw1[1024], lw2[1024], lw0[32];
    const int tid  = threadIdx.x;
    const int lane = tid & 63;

    // ================= BUILD PHASE (blocks 0..335, identical math to r11) ==
    if (blockIdx.x < NBUILD_BLK) {
#pragma unroll
        for (int r = 0; r < 4; ++r) {
            int o = r * 256 + tid;
            lmu[o]  = mu[o];
            lsig[o] = sigma[o];
            lw1[o]  = Wk1k0[o];
            lw2[o]  = Wk2k1[o];
        }
        if (tid < 32) lw0[tid] = Wk0[tid];
        __syncthreads();

        int wid = __builtin_amdgcn_readfirstlane((blockIdx.x * 256 + tid) >> 6);
        const int HALF = KK * NCH;                 // 672 waves per table
        const int table = wid >= HALF;             // scalar
        int rem   = table ? wid - HALF : wid;
        int k1    = rem / NCH;
        int chunk = rem - k1 * NCH;
        int i     = chunk * 64 + lane;             // per-lane grid index
        float x   = __builtin_fmaf((float)i, GH, XLO);

        const float LOG2E = 1.4426950408889634f;
        const float INV_SQRT_2PI = 0.3989422804014327f;

        float q[KK];
        float m = -3.0e38f;
#pragma unroll
        for (int k = 0; k < KK; ++k) {
            int idx = table ? (k1 * KK + k) : (k * KK + k1);   // wave-uniform
            float muv = lmu[idx];                              // ds broadcast
            float sv  = lsig[idx];
            float wv  = table ? (lw1[idx] * lw0[k]) : lw2[idx];
            float inv_s = 1.0f / sv;
            float z = (x - muv) * inv_s;
            float qq = __builtin_fmaf(-0.5f * LOG2E * z, z,
                                      hw_log2(wv * INV_SQRT_2PI * inv_s));
            q[k] = qq;
            m = fmaxf(m, qq);
        }
        float s = 0.0f;
#pragma unroll
        for (int k = 0; k < KK; ++k) s += hw_exp2(q[k] - m);
        float val = m + hw_log2(s);

        float* df = table ? Hp : Gp;               // pair array, float view
        df[(i * KK + k1) * 2] = val;               // pair[i].x = val[i]
        if (i > 0)
            df[((i - 1) * KK + k1) * 2 + 1] = val; // pair[i-1].y = val[i]

        // ---- release: stores drained by __syncthreads (write-through L1);
        //      one L2-writeback fence, then arrive.
        __syncthreads();
        if (tid == 0) {
            __threadfence();
            __hip_atomic_fetch_add(ctr, 1u, __ATOMIC_RELAXED,
                                   __HIP_MEMORY_SCOPE_AGENT);
        }
    }

    // ================= WAIT FOR TABLES (relaxed polls, no cache ops) =======
    if (tid == 0) {
        while (__hip_atomic_load(ctr, __ATOMIC_RELAXED,
                                 __HIP_MEMORY_SCOPE_AGENT)
               < (unsigned)NBUILD_BLK) {
            __builtin_amdgcn_s_sleep(8);
        }
        __threadfence();        // acquire ONCE: drop stale lines (L1+L2)
    }
    __syncthreads();

    // ================= MAIN PHASE (identical math to r11) ==================
    const float4* G4 = (const float4*)Gp;
    const float4* H4 = (const float4*)Hp;
    const int kl8 = tid & 7;                   // which k1-quad this lane owns
    const int grp = (tid & 63) >> 3;           // sample slot within wave
    const int gw  = (blockIdx.x * 256 + tid) >> 6;
    const int stride = NBLK * 32;              // samples per grid pass
    const float LN2 = 0.6931471805599453f;

#pragma unroll 2
    for (int s = gw * 8 + grp; s < ntot; s += stride) {
        float2 x = X[s];                       // broadcast within 8-lane group

        float u1 = (x.y - XLO) * INVH;
        float u0 = (x.x - XLO) * INVH;
        int i1 = (int)u1; i1 = i1 < 0 ? 0 : (i1 > NG - 2 ? NG - 2 : i1);
        int i0 = (int)u0; i0 = i0 < 0 ? 0 : (i0 > NG - 2 ? NG - 2 : i0);
        float f1 = fminf(fmaxf(u1 - (float)i1, 0.0f), 1.0f);
        float f0 = fminf(fmaxf(u0 - (float)i0, 0.0f), 1.0f);

        int og = i1 * 16 + kl8 * 2;            // row = 32 float2 = 16 float4
        int oh = i0 * 16 + kl8 * 2;
        float4 ga = G4[og], gb = G4[og + 1];   // 4 k1's, both lerp endpoints
        float4 ha = H4[oh], hb = H4[oh + 1];

        float q0 = __builtin_fmaf(f1, ga.y - ga.x, ga.x)
                 + __builtin_fmaf(f0, ha.y - ha.x, ha.x);
        float q1 = __builtin_fmaf(f1, ga.w - ga.z, ga.z)
                 + __builtin_fmaf(f0, ha.w - ha.z, ha.z);
        float q2 = __builtin_fmaf(f1, gb.y - gb.x, gb.x)
                 + __builtin_fmaf(f0, hb.y - hb.x, hb.x);
        float q3 = __builtin_fmaf(f1, gb.w - gb.z, gb.z)
                 + __builtin_fmaf(f0, hb.w - hb.z, hb.z);
        float e = (hw_exp2(q0) + hw_exp2(q1)) + (hw_exp2(q2) + hw_exp2(q3));

        // sum over the 8-lane group (3 stages)
        e += __shfl_xor(e, 1, 8);
        e += __shfl_xor(e, 2, 8);
        e += __shfl_xor(e, 4, 8);

        if (kl8 == 0) out[s] = LN2 * hw_log2(e);
    }
}

extern "C" void kernel_launch(void* const* d_in, const int* in_sizes, int n_in,
                              void* d_out, int out_size, void* d_ws, size_t ws_size,
                              hipStream_t stream) {
    const float* X     = (const float*)d_in[0];
    const float* Wk0   = (const float*)d_in[1];
    const float* Wk1k0 = (const float*)d_in[2];
    const float* Wk2k1 = (const float*)d_in[3];
    const float* mu    = (const float*)d_in[4];
    const float* sigma = (const float*)d_in[5];
    float* out = (float*)d_out;

    // pair tables: NG*KK*8 B = 336 KB each; barrier counter after them
    const size_t TBL = (size_t)NG * KK * 8;
    float*    Gp  = (float*)d_ws;
    float*    Hp  = (float*)((char*)d_ws + TBL);
    unsigned* ctr = (unsigned*)((char*)d_ws + 2 * TBL);

    int ntot = in_sizes[0] / 2;  // N = 131072

    hipMemsetAsync(ctr, 0, sizeof(unsigned), stream);
    tt_fused<<<NBLK, 256, 0, stream>>>(
        (const float2*)X, Wk0, Wk1k0, Wk2k1, mu, sigma, Gp, Hp, ctr, out, ntot);
}

// Round 14
// 15.393 us; speedup vs baseline: 54.0712x; 6.9429x over previous
//
#include <hip/hip_runtime.h>
#include <hip/hip_bf16.h>
#include <math.h>

#define KK   32
#define NG   1344        // grid points per table (168 blocks * 8 pts)
#define XLO  (-6.5f)
#define GH   0.01f
#define INVH 100.0f

__device__ __forceinline__ float hw_exp2(float x) {
#if __has_builtin(__builtin_amdgcn_exp2f)
    return __builtin_amdgcn_exp2f(x);
#else
    float r;
    asm("v_exp_f32 %0, %1" : "=v"(r) : "v"(x));
    return r;
#endif
}

__device__ __forceinline__ float hw_log2(float x) {
#if __has_builtin(__builtin_amdgcn_logf)
    return __builtin_amdgcn_logf(x);
#else
    float r;
    asm("v_log_f32 %0, %1" : "=v"(r) : "v"(x));
    return r;
#endif
}

// Two-kernel structure (r11): fusion via grid-sync is strictly worse on this
// 8-XCD chip (r12: 832us, r13: 106us — cross-XCD fence/poll serialization
// dwarfs the ~5us dispatch overhead it saves).
//
// Build v3: k1-PER-LANE mapping. r8-r13 builds had grid-point-per-lane, so
// the pair stores strided 256B across lanes -> 64 partial lines per store
// instr -> ~11MB fetch + ~22MB writeback (seen as r12/r13's 8.6/18MB; ~3-4us
// of HBM time). Now a 32-lane half stores 32 consecutive float2s (4 lines).
// LDS params padded [32][33]: G reads row=k (uniform -> consecutive cols),
// H reads row=lane ((lane*33+k)%32 distinct -> conflict-free).
__global__ __launch_bounds__(256) void tt_build_grid(
        const float* __restrict__ Wk0,
        const float* __restrict__ Wk1k0,
        const float* __restrict__ Wk2k1,
        const float* __restrict__ mu,
        const float* __restrict__ sigma,
        float* __restrict__ Gp,   // [NG][KK] float2 pairs (val[i], val[i+1])
        float* __restrict__ Hp) {
    __shared__ float lmu[1056], lsig[1056], lwp[1056], lw0[32];
    const int tid   = threadIdx.x;
    const int table = blockIdx.x >= (NG / 8);          // uniform per block
    const int blocal = table ? blockIdx.x - (NG / 8) : blockIdx.x;

    // stage row-major [32][32] -> padded [32][33]; consecutive lanes write
    // consecutive LDS addresses within a row -> conflict-free
#pragma unroll
    for (int r = 0; r < 4; ++r) {
        int o = r * 256 + tid;
        int po = (o >> 5) * 33 + (o & 31);
        lmu[po]  = mu[o];
        lsig[po] = sigma[o];
        lwp[po]  = table ? Wk1k0[o] : Wk2k1[o];
    }
    if (tid < 32) lw0[tid] = Wk0[tid];
    __syncthreads();

    const int k1 = tid & 31;                 // per-lane k1
    const int i  = blocal * 8 + (tid >> 5);  // grid point per 32-lane group
    float x = __builtin_fmaf((float)i, GH, XLO);

    const float LOG2E = 1.4426950408889634f;
    const float INV_SQRT_2PI = 0.3989422804014327f;

    float q[KK];
    float m = -3.0e38f;
#pragma unroll
    for (int k = 0; k < KK; ++k) {
        int idx = table ? (k1 * 33 + k) : (k * 33 + k1);   // padded
        float muv = lmu[idx];
        float sv  = lsig[idx];
        float wv  = table ? (lwp[idx] * lw0[k]) : lwp[idx];
        float inv_s = 1.0f / sv;
        float z = (x - muv) * inv_s;
        float qq = __builtin_fmaf(-0.5f * LOG2E * z, z,
                                  hw_log2(wv * INV_SQRT_2PI * inv_s));
        q[k] = qq;
        m = fmaxf(m, qq);
    }
    float s = 0.0f;
#pragma unroll
    for (int k = 0; k < KK; ++k) s += hw_exp2(q[k] - m);
    float val = m + hw_log2(s);

    float* df = table ? Hp : Gp;             // pair array, float view
    // coalesced: 32 lanes cover one 256B pair-row, alternate dwords
    df[(i * KK + k1) * 2] = val;             // pair[i].x = val[i]
    if (i > 0)
        df[((i - 1) * KK + k1) * 2 + 1] = val; // pair[i-1].y = val[i]
}

// Main (r11, unchanged): 8 lanes per sample, lane owns 4 k1's via two float4
// pair loads (both lerp endpoints in one load), 3-stage shfl sum, grid-stride.
__global__ __launch_bounds__(256) void tt_main(const float2* __restrict__ X,
                                               const float4* __restrict__ G4,
                                               const float4* __restrict__ H4,
                                               float* __restrict__ out,
                                               int ntot) {
    const int kl8 = threadIdx.x & 7;           // which k1-quad this lane owns
    const int grp = (threadIdx.x & 63) >> 3;   // sample slot within wave
    const int gw  = (blockIdx.x * 256 + threadIdx.x) >> 6;
    const int stride = gridDim.x * 32;         // samples per grid pass
    const float LN2 = 0.6931471805599453f;

#pragma unroll 2
    for (int s = gw * 8 + grp; s < ntot; s += stride) {
        float2 x = X[s];                       // broadcast within 8-lane group

        float u1 = (x.y - XLO) * INVH;
        float u0 = (x.x - XLO) * INVH;
        int i1 = (int)u1; i1 = i1 < 0 ? 0 : (i1 > NG - 2 ? NG - 2 : i1);
        int i0 = (int)u0; i0 = i0 < 0 ? 0 : (i0 > NG - 2 ? NG - 2 : i0);
        float f1 = fminf(fmaxf(u1 - (float)i1, 0.0f), 1.0f);
        float f0 = fminf(fmaxf(u0 - (float)i0, 0.0f), 1.0f);

        int og = i1 * 16 + kl8 * 2;            // row = 32 float2 = 16 float4
        int oh = i0 * 16 + kl8 * 2;
        float4 ga = G4[og], gb = G4[og + 1];   // 4 k1's, both lerp endpoints
        float4 ha = H4[oh], hb = H4[oh + 1];

        float q0 = __builtin_fmaf(f1, ga.y - ga.x, ga.x)
                 + __builtin_fmaf(f0, ha.y - ha.x, ha.x);
        float q1 = __builtin_fmaf(f1, ga.w - ga.z, ga.z)
                 + __builtin_fmaf(f0, ha.w - ha.z, ha.z);
        float q2 = __builtin_fmaf(f1, gb.y - gb.x, gb.x)
                 + __builtin_fmaf(f0, hb.y - hb.x, hb.x);
        float q3 = __builtin_fmaf(f1, gb.w - gb.z, gb.z)
                 + __builtin_fmaf(f0, hb.w - hb.z, hb.z);
        float e = (hw_exp2(q0) + hw_exp2(q1)) + (hw_exp2(q2) + hw_exp2(q3));

        // sum over the 8-lane group (3 stages)
        e += __shfl_xor(e, 1, 8);
        e += __shfl_xor(e, 2, 8);
        e += __shfl_xor(e, 4, 8);

        if (kl8 == 0) out[s] = LN2 * hw_log2(e);
    }
}

extern "C" void kernel_launch(void* const* d_in, const int* in_sizes, int n_in,
                              void* d_out, int out_size, void* d_ws, size_t ws_size,
                              hipStream_t stream) {
    const float* X     = (const float*)d_in[0];
    const float* Wk0   = (const float*)d_in[1];
    const float* Wk1k0 = (const float*)d_in[2];
    const float* Wk2k1 = (const float*)d_in[3];
    const float* mu    = (const float*)d_in[4];
    const float* sigma = (const float*)d_in[5];
    float* out = (float*)d_out;

    // pair tables: NG*KK*8 B = 336 KB each
    float* Gp = (float*)d_ws;
    float* Hp = (float*)((char*)d_ws + (size_t)NG * KK * 8);

    int ntot = in_sizes[0] / 2;  // N = 131072

    // 336 blocks: 168 per table, 8 grid points per block
    tt_build_grid<<<2 * (NG / 8), 256, 0, stream>>>(
        Wk0, Wk1k0, Wk2k1, mu, sigma, Gp, Hp);

    // 2048 blocks (8/CU), 8 samples/wave/pass, 2 passes
    tt_main<<<2048, 256, 0, stream>>>(
        (const float2*)X, (const float4*)Gp, (const float4*)Hp, out, ntot);
}